// Round 3
// baseline (1222.069 us; speedup 1.0000x reference)
//
#include <hip/hip_runtime.h>
#include <hip/hip_bf16.h>
#include <cstddef>
#include <cstdint>

#define BSZ   4
#define SEQ   4096
#define DIN   1024
#define HDIM  1024
#define MTOT  (BSZ * SEQ)            // 16384 rows
#define NELE  ((size_t)MTOT * HDIM)  // 16,777,216 elements per [bs,S,H] tensor
#define NCH   64                     // scan chunks
#define CL    (SEQ / NCH)            // 64 steps per chunk

// bf16 bits <-> float (used only for the reduced-precision scratch fallback)
__device__ __forceinline__ float bf2f(unsigned short u) {
    union { unsigned int i; float f; } v;
    v.i = ((unsigned int)u) << 16;
    return v.f;
}
__device__ __forceinline__ unsigned short f2bf(float f) {
    union { float f; unsigned int i; } v; v.f = f;
    unsigned int lsb = (v.i >> 16) & 1u;
    v.i += 0x7fffu + lsb;            // round-to-nearest-even
    return (unsigned short)(v.i >> 16);
}

// ---------- storage-type helpers (fp32 or bf16 scratch) ----------
__device__ __forceinline__ float ldv(const float* p, size_t i) { return p[i]; }
__device__ __forceinline__ float ldv(const unsigned short* p, size_t i) { return bf2f(p[i]); }
__device__ __forceinline__ void stv(float* p, size_t i, float v) { p[i] = v; }
__device__ __forceinline__ void stv(unsigned short* p, size_t i, float v) { p[i] = f2bf(v); }

// ---------- fused GEMM (x@Wz^T, x@Wh^T) + activations ----------
// a = sigmoid(-k) = 1-z ; b = sigmoid(k) * g(ph); g(x) = x>=0 ? x+0.5 : sigmoid(x)
template <typename T>
__global__ __launch_bounds__(256) void gemm_act_kernel(
    const float* __restrict__ x, const float* __restrict__ Wz,
    const float* __restrict__ bz, const float* __restrict__ Wh,
    const float* __restrict__ bh, T* __restrict__ aArr, T* __restrict__ bArr)
{
    __shared__ float xs[16][65];
    __shared__ float zsm[16][65];
    __shared__ float hsm[16][65];
    const int tid = threadIdx.x;
    const int m0 = blockIdx.y << 6;   // over 16384 rows
    const int n0 = blockIdx.x << 6;   // over 1024 cols
    const int row = tid >> 2;         // 0..63
    const int cg  = (tid & 3) << 2;   // 0,4,8,12 (element offset within 16-wide k-slab)
    const int tx = tid & 15;
    const int ty = tid >> 4;

    float acc1[4][4];
    float acc2[4][4];
#pragma unroll
    for (int i = 0; i < 4; ++i)
#pragma unroll
        for (int j = 0; j < 4; ++j) { acc1[i][j] = 0.f; acc2[i][j] = 0.f; }

    const float* xp = x  + (size_t)(m0 + row) * DIN + cg;
    const float* zp = Wz + (size_t)(n0 + row) * DIN + cg;
    const float* hp = Wh + (size_t)(n0 + row) * DIN + cg;

    for (int k0 = 0; k0 < DIN; k0 += 16) {
        const float4 xv = *(const float4*)(xp + k0);
        const float4 zv = *(const float4*)(zp + k0);
        const float4 hv = *(const float4*)(hp + k0);
        __syncthreads();
        xs[cg + 0][row] = xv.x; xs[cg + 1][row] = xv.y;
        xs[cg + 2][row] = xv.z; xs[cg + 3][row] = xv.w;
        zsm[cg + 0][row] = zv.x; zsm[cg + 1][row] = zv.y;
        zsm[cg + 2][row] = zv.z; zsm[cg + 3][row] = zv.w;
        hsm[cg + 0][row] = hv.x; hsm[cg + 1][row] = hv.y;
        hsm[cg + 2][row] = hv.z; hsm[cg + 3][row] = hv.w;
        __syncthreads();
#pragma unroll
        for (int kk = 0; kk < 16; ++kk) {
            float xf[4], zf[4], hf[4];
#pragma unroll
            for (int i = 0; i < 4; ++i) xf[i] = xs[kk][(ty << 2) + i];
#pragma unroll
            for (int j = 0; j < 4; ++j) {
                zf[j] = zsm[kk][(tx << 2) + j];
                hf[j] = hsm[kk][(tx << 2) + j];
            }
#pragma unroll
            for (int i = 0; i < 4; ++i)
#pragma unroll
                for (int j = 0; j < 4; ++j) {
                    acc1[i][j] = fmaf(xf[i], zf[j], acc1[i][j]);
                    acc2[i][j] = fmaf(xf[i], hf[j], acc2[i][j]);
                }
        }
    }

#pragma unroll
    for (int i = 0; i < 4; ++i) {
        const size_t m = (size_t)m0 + (ty << 2) + i;
#pragma unroll
        for (int j = 0; j < 4; ++j) {
            const int n = n0 + (tx << 2) + j;
            const float kpre = acc1[i][j] + bz[n];
            const float hpre = acc2[i][j] + bh[n];
            const float z  = 1.0f / (1.0f + expf(-kpre));
            const float ac = 1.0f / (1.0f + expf(kpre));
            const float g  = (hpre >= 0.0f) ? (hpre + 0.5f)
                                            : (1.0f / (1.0f + expf(-hpre)));
            const size_t idx = m * HDIM + n;
            stv(aArr, idx, ac);
            stv(bArr, idx, z * g);
        }
    }
}

// ---------- Phase A: per-chunk affine composition (A,B) ----------
template <typename T>
__global__ __launch_bounds__(256) void scan_phaseA(
    const T* __restrict__ aArr, const T* __restrict__ bArr,
    float* __restrict__ carryA, float* __restrict__ carryB)
{
    const int h  = blockIdx.x * 256 + threadIdx.x; // 0..1023
    const int c  = blockIdx.y;                     // chunk 0..63
    const int bi = blockIdx.z;                     // batch 0..3
    const size_t base = ((size_t)bi * SEQ + (size_t)c * CL) * HDIM + h;
    float A = 1.0f, B = 0.0f;
#pragma unroll 4
    for (int t = 0; t < CL; ++t) {
        const float af = ldv(aArr, base + (size_t)t * HDIM);
        const float bf = ldv(bArr, base + (size_t)t * HDIM);
        A *= af;
        B = fmaf(af, B, bf);
    }
    const size_t ci = ((size_t)c * BSZ + bi) * HDIM + h;
    carryA[ci] = A;
    carryB[ci] = B;
}

// ---------- Phase B: sequential scan over chunk carries ----------
__global__ __launch_bounds__(256) void scan_phaseB(
    const float* __restrict__ h0, const float* __restrict__ carryA,
    const float* __restrict__ carryB, float* __restrict__ hin)
{
    const int h  = blockIdx.x * 256 + threadIdx.x;
    const int bi = blockIdx.y;
    const float v = h0[(size_t)bi * HDIM + h];
    float hr = (v >= 0.0f) ? (v + 0.5f) : (1.0f / (1.0f + expf(-v)));
    for (int c = 0; c < NCH; ++c) {
        const size_t ci = ((size_t)c * BSZ + bi) * HDIM + h;
        hin[ci] = hr;
        hr = fmaf(carryA[ci], hr, carryB[ci]);
    }
}

// ---------- Phase C: replay chunk with known h_in, write fp32 out ----------
template <typename T>
__global__ __launch_bounds__(256) void scan_phaseC(
    const T* __restrict__ aArr, const T* __restrict__ bArr,
    const float* __restrict__ hin, float* __restrict__ out)
{
    const int h  = blockIdx.x * 256 + threadIdx.x;
    const int c  = blockIdx.y;
    const int bi = blockIdx.z;
    const size_t base = ((size_t)bi * SEQ + (size_t)c * CL) * HDIM + h;
    const size_t ci = ((size_t)c * BSZ + bi) * HDIM + h;
    float hr = hin[ci];
#pragma unroll 4
    for (int t = 0; t < CL; ++t) {
        const size_t idx = base + (size_t)t * HDIM;
        const float af = ldv(aArr, idx);
        const float bf = ldv(bArr, idx);
        hr = fmaf(af, hr, bf);
        out[idx] = hr;
    }
}

// ---------- launch ----------
template <typename T>
static void run_pipeline(const float* x, const float* h0,
                         const float* Wz, const float* bz,
                         const float* Wh, const float* bh,
                         float* out, void* d_ws, hipStream_t stream)
{
    T* aArr = (T*)d_ws;
    T* bArr = aArr + NELE;
    float* tail = (float*)(bArr + NELE);
    float* carryA = tail;
    float* carryB = carryA + (size_t)NCH * BSZ * HDIM;
    float* hin    = carryB + (size_t)NCH * BSZ * HDIM;

    dim3 gGrid(HDIM / 64, MTOT / 64);
    gemm_act_kernel<T><<<gGrid, 256, 0, stream>>>(x, Wz, bz, Wh, bh, aArr, bArr);

    dim3 aGrid(HDIM / 256, NCH, BSZ);
    scan_phaseA<T><<<aGrid, 256, 0, stream>>>(aArr, bArr, carryA, carryB);

    dim3 bGrid(HDIM / 256, BSZ);
    scan_phaseB<<<bGrid, 256, 0, stream>>>(h0, carryA, carryB, hin);

    scan_phaseC<T><<<aGrid, 256, 0, stream>>>(aArr, bArr, hin, out);
}

extern "C" void kernel_launch(void* const* d_in, const int* in_sizes, int n_in,
                              void* d_out, int out_size, void* d_ws, size_t ws_size,
                              hipStream_t stream)
{
    const float* x  = (const float*)d_in[0];
    const float* h0 = (const float*)d_in[1];
    const float* Wz = (const float*)d_in[2];
    const float* bz = (const float*)d_in[3];
    const float* Wh = (const float*)d_in[4];
    const float* bh = (const float*)d_in[5];
    float* out = (float*)d_out;

    const size_t tailBytes = 3ull * NCH * BSZ * HDIM * sizeof(float); // carries + hin
    const size_t needF32 = 2ull * NELE * sizeof(float) + tailBytes;

    if (ws_size >= needF32) {
        run_pipeline<float>(x, h0, Wz, bz, Wh, bh, out, d_ws, stream);
    } else {
        run_pipeline<unsigned short>(x, h0, Wz, bz, Wh, bh, out, d_ws, stream);
    }
}

// Round 4
// 335.639 us; speedup vs baseline: 3.6410x; 3.6410x over previous
//
#include <hip/hip_runtime.h>
#include <cstddef>
#include <cstdint>

#define BSZ   4
#define SEQ   4096
#define DIN   1024
#define HDIM  1024
#define MTOT  (BSZ * SEQ)            // 16384 rows
#define NELE  ((size_t)MTOT * HDIM)  // 16.7M elements per [bs,S,H] tensor
#define NCH   64                     // scan chunks
#define CL    (SEQ / NCH)            // 64 steps per chunk

#define BM 128
#define BN 64
#define BK 32
#define LDK 40                        // padded LDS row stride in ushorts (80B: 2-way banks only)

using bf16x8 = __attribute__((ext_vector_type(8))) __bf16;
using f32x4  = __attribute__((ext_vector_type(4))) float;

// ---------- bf16 bit helpers ----------
__device__ __forceinline__ float bf2f(unsigned short u) {
    union { unsigned int i; float f; } v;
    v.i = ((unsigned int)u) << 16;
    return v.f;
}
__device__ __forceinline__ unsigned short f2bf(float f) {  // RNE (epilogue/scratch)
    union { float f; unsigned int i; } v; v.f = f;
    unsigned int lsb = (v.i >> 16) & 1u;
    v.i += 0x7fffu + lsb;
    return (unsigned short)(v.i >> 16);
}
// cheap round-half-up pack of two floats -> (lo=a, hi=b) bf16 pair (staging hot path)
__device__ __forceinline__ unsigned int pk2(float a, float b) {
    union { float f; unsigned int i; } ua, ub; ua.f = a; ub.f = b;
    return ((ua.i + 0x8000u) >> 16) | ((ub.i + 0x8000u) & 0xffff0000u);
}
__device__ __forceinline__ uint4 pack8(const float4& u, const float4& v) {
    uint4 r;
    r.x = pk2(u.x, u.y); r.y = pk2(u.z, u.w);
    r.z = pk2(v.x, v.y); r.w = pk2(v.z, v.w);
    return r;
}

// ---------- interleaved (a,b) scratch: fp32 or bf16 ----------
__device__ __forceinline__ float2 ld2(const float* ab, size_t idx) {
    return ((const float2*)ab)[idx];
}
__device__ __forceinline__ float2 ld2(const unsigned short* ab, size_t idx) {
    const unsigned int u = ((const unsigned int*)ab)[idx];
    float2 r; r.x = bf2f((unsigned short)(u & 0xffffu)); r.y = bf2f((unsigned short)(u >> 16));
    return r;
}
__device__ __forceinline__ void st2(float* ab, size_t idx, float a, float b) {
    ((float2*)ab)[idx] = make_float2(a, b);
}
__device__ __forceinline__ void st2(unsigned short* ab, size_t idx, float a, float b) {
    ((unsigned int*)ab)[idx] = (unsigned int)f2bf(a) | ((unsigned int)f2bf(b) << 16);
}

// ---------- MFMA GEMM: a = sigma(-k), b = sigma(k)*g(ph), interleaved ----------
template <typename T>
__global__ __launch_bounds__(256) void gemm_act_mfma(
    const float* __restrict__ x, const float* __restrict__ Wz,
    const float* __restrict__ bz, const float* __restrict__ Wh,
    const float* __restrict__ bh, T* __restrict__ ab)
{
    __shared__ unsigned short xs[BM * LDK];
    __shared__ unsigned short zs[BN * LDK];
    __shared__ unsigned short hs[BN * LDK];

    const int tid  = threadIdx.x;
    const int wid  = tid >> 6;
    const int lane = tid & 63;
    const int lm   = lane & 15;   // A row / B col / C col
    const int q    = lane >> 4;   // k-octet for frags; row-quad for C

    const int m0 = blockIdx.y * BM;
    const int n0 = blockIdx.x * BN;

    // staging assignment
    const int xrow = tid >> 1;          // 0..127
    const int xk   = (tid & 1) << 4;    // 0,16
    const int wrow = tid >> 2;          // 0..63
    const int wk   = (tid & 3) << 3;    // 0,8,16,24

    const float* xp = x  + (size_t)(m0 + xrow) * DIN + xk;
    const float* zp = Wz + (size_t)(n0 + wrow) * DIN + wk;
    const float* hp = Wh + (size_t)(n0 + wrow) * DIN + wk;

    const int xoff = xrow * LDK + xk;
    const int woff = wrow * LDK + wk;
    const int aoff0 = (wid * 32 + lm) * LDK + q * 8;   // m-tile 0 of this wave
    const int aoff1 = aoff0 + 16 * LDK;                // m-tile 1

    f32x4 acc1[2][4], acc2[2][4];
#pragma unroll
    for (int mt = 0; mt < 2; ++mt)
#pragma unroll
        for (int nt = 0; nt < 4; ++nt) {
            acc1[mt][nt] = (f32x4){0.f, 0.f, 0.f, 0.f};
            acc2[mt][nt] = (f32x4){0.f, 0.f, 0.f, 0.f};
        }

    for (int k0 = 0; k0 < DIN; k0 += BK) {
        // global fp32 loads (overlap with other waves' MFMA)
        float4 xv0 = *(const float4*)(xp + k0 + 0);
        float4 xv1 = *(const float4*)(xp + k0 + 4);
        float4 xv2 = *(const float4*)(xp + k0 + 8);
        float4 xv3 = *(const float4*)(xp + k0 + 12);
        float4 zv0 = *(const float4*)(zp + k0 + 0);
        float4 zv1 = *(const float4*)(zp + k0 + 4);
        float4 hv0 = *(const float4*)(hp + k0 + 0);
        float4 hv1 = *(const float4*)(hp + k0 + 4);
        const uint4 px0 = pack8(xv0, xv1);
        const uint4 px1 = pack8(xv2, xv3);
        const uint4 pz  = pack8(zv0, zv1);
        const uint4 ph  = pack8(hv0, hv1);

        __syncthreads();   // previous tile fully consumed
        *(uint4*)&xs[xoff]     = px0;
        *(uint4*)&xs[xoff + 8] = px1;
        *(uint4*)&zs[woff]     = pz;
        *(uint4*)&hs[woff]     = ph;
        __syncthreads();   // tile visible

        const bf16x8 a0 = *(const bf16x8*)&xs[aoff0];
        const bf16x8 a1 = *(const bf16x8*)&xs[aoff1];
#pragma unroll
        for (int nt = 0; nt < 4; ++nt) {
            const int boff = (nt * 16 + lm) * LDK + q * 8;
            const bf16x8 bz8 = *(const bf16x8*)&zs[boff];
            const bf16x8 bh8 = *(const bf16x8*)&hs[boff];
            acc1[0][nt] = __builtin_amdgcn_mfma_f32_16x16x32_bf16(a0, bz8, acc1[0][nt], 0, 0, 0);
            acc1[1][nt] = __builtin_amdgcn_mfma_f32_16x16x32_bf16(a1, bz8, acc1[1][nt], 0, 0, 0);
            acc2[0][nt] = __builtin_amdgcn_mfma_f32_16x16x32_bf16(a0, bh8, acc2[0][nt], 0, 0, 0);
            acc2[1][nt] = __builtin_amdgcn_mfma_f32_16x16x32_bf16(a1, bh8, acc2[1][nt], 0, 0, 0);
        }
    }

    // epilogue: C layout col = lane&15, row = q*4 + reg
#pragma unroll
    for (int mt = 0; mt < 2; ++mt) {
        const int mb = m0 + wid * 32 + mt * 16 + q * 4;
#pragma unroll
        for (int nt = 0; nt < 4; ++nt) {
            const int n = n0 + nt * 16 + lm;
            const float bzv = bz[n];
            const float bhv = bh[n];
#pragma unroll
            for (int r = 0; r < 4; ++r) {
                const float kpre = acc1[mt][nt][r] + bzv;
                const float hpre = acc2[mt][nt][r] + bhv;
                const float ez   = expf(-kpre);
                const float zinv = 1.0f / (1.0f + ez);   // z = sigmoid(k)
                const float av   = ez * zinv;            // 1-z = sigmoid(-k)
                const float g    = (hpre >= 0.0f) ? (hpre + 0.5f)
                                                  : (1.0f / (1.0f + expf(-hpre)));
                st2(ab, (size_t)(mb + r) * HDIM + n, av, zinv * g);
            }
        }
    }
}

// ---------- Phase A: per-chunk affine composition (A,B) ----------
template <typename T>
__global__ __launch_bounds__(256) void scan_phaseA(
    const T* __restrict__ ab, float* __restrict__ carryA, float* __restrict__ carryB)
{
    const int h  = blockIdx.x * 256 + threadIdx.x; // 0..1023
    const int c  = blockIdx.y;                     // chunk
    const int bi = blockIdx.z;                     // batch
    const size_t base = ((size_t)bi * SEQ + (size_t)c * CL) * HDIM + h;
    float A = 1.0f, B = 0.0f;
#pragma unroll 4
    for (int t = 0; t < CL; ++t) {
        const float2 v = ld2(ab, base + (size_t)t * HDIM);
        A *= v.x;
        B = fmaf(v.x, B, v.y);
    }
    const size_t ci = ((size_t)c * BSZ + bi) * HDIM + h;
    carryA[ci] = A;
    carryB[ci] = B;
}

// ---------- Phase B: sequential scan over chunk carries ----------
__global__ __launch_bounds__(256) void scan_phaseB(
    const float* __restrict__ h0, const float* __restrict__ carryA,
    const float* __restrict__ carryB, float* __restrict__ hin)
{
    const int h  = blockIdx.x * 256 + threadIdx.x;
    const int bi = blockIdx.y;
    const float v = h0[(size_t)bi * HDIM + h];
    float hr = (v >= 0.0f) ? (v + 0.5f) : (1.0f / (1.0f + expf(-v)));
    for (int c = 0; c < NCH; ++c) {
        const size_t ci = ((size_t)c * BSZ + bi) * HDIM + h;
        hin[ci] = hr;
        hr = fmaf(carryA[ci], hr, carryB[ci]);
    }
}

// ---------- Phase C: replay chunk with known h_in, write fp32 out ----------
template <typename T>
__global__ __launch_bounds__(256) void scan_phaseC(
    const T* __restrict__ ab, const float* __restrict__ hin, float* __restrict__ out)
{
    const int h  = blockIdx.x * 256 + threadIdx.x;
    const int c  = blockIdx.y;
    const int bi = blockIdx.z;
    const size_t base = ((size_t)bi * SEQ + (size_t)c * CL) * HDIM + h;
    const size_t ci = ((size_t)c * BSZ + bi) * HDIM + h;
    float hr = hin[ci];
#pragma unroll 4
    for (int t = 0; t < CL; ++t) {
        const size_t idx = base + (size_t)t * HDIM;
        const float2 v = ld2(ab, idx);
        hr = fmaf(v.x, hr, v.y);
        out[idx] = hr;
    }
}

// ---------- launch ----------
template <typename T>
static void run_pipeline(const float* x, const float* h0,
                         const float* Wz, const float* bz,
                         const float* Wh, const float* bh,
                         float* out, void* d_ws, hipStream_t stream)
{
    T* ab = (T*)d_ws;                       // interleaved (a,b): 2*NELE elements
    float* tail   = (float*)(ab + 2 * NELE);
    float* carryA = tail;
    float* carryB = carryA + (size_t)NCH * BSZ * HDIM;
    float* hin    = carryB + (size_t)NCH * BSZ * HDIM;

    dim3 gGrid(HDIM / BN, MTOT / BM);
    gemm_act_mfma<T><<<gGrid, 256, 0, stream>>>(x, Wz, bz, Wh, bh, ab);

    dim3 aGrid(HDIM / 256, NCH, BSZ);
    scan_phaseA<T><<<aGrid, 256, 0, stream>>>(ab, carryA, carryB);

    dim3 bGrid(HDIM / 256, BSZ);
    scan_phaseB<<<bGrid, 256, 0, stream>>>(h0, carryA, carryB, hin);

    scan_phaseC<T><<<aGrid, 256, 0, stream>>>(ab, hin, out);
}

extern "C" void kernel_launch(void* const* d_in, const int* in_sizes, int n_in,
                              void* d_out, int out_size, void* d_ws, size_t ws_size,
                              hipStream_t stream)
{
    const float* x  = (const float*)d_in[0];
    const float* h0 = (const float*)d_in[1];
    const float* Wz = (const float*)d_in[2];
    const float* bz = (const float*)d_in[3];
    const float* Wh = (const float*)d_in[4];
    const float* bh = (const float*)d_in[5];
    float* out = (float*)d_out;

    const size_t tailBytes = 3ull * NCH * BSZ * HDIM * sizeof(float);
    const size_t needF32 = 2ull * NELE * sizeof(float) + tailBytes;

    if (ws_size >= needF32) {
        run_pipeline<float>(x, h0, Wz, bz, Wh, bh, out, d_ws, stream);
    } else {
        run_pipeline<unsigned short>(x, h0, Wz, bz, Wh, bh, out, d_ws, stream);
    }
}